// Round 1
// baseline (615.399 us; speedup 1.0000x reference)
//
#include <hip/hip_runtime.h>
#include <hip/hip_bf16.h>

#define B_ROWS 16384
#define D_DIM  3072
#define H_DIM  128
#define O_DIM  10
#define E_NUM  8

typedef __hip_bfloat16 bf16;
typedef __attribute__((ext_vector_type(8))) short short8;   // 8 bf16 = 4 VGPRs (MFMA A/B frag)
typedef __attribute__((ext_vector_type(4))) float floatx4;  // MFMA C/D frag

// ---------------------------------------------------------------------------
// K0: transpose+convert  in[e][R][C] fp32  ->  out[e][C][R] bf16
// ---------------------------------------------------------------------------
__global__ void transpose_bf16_kernel(const float* __restrict__ in,
                                      bf16* __restrict__ out, int R, int C) {
    int e = blockIdx.z;
    const float* inp = in + (size_t)e * R * C;
    bf16* outp = out + (size_t)e * R * C;
    __shared__ float tile[32][33];
    int tx = threadIdx.x;   // 0..31
    int ty = threadIdx.y;   // 0..7
    int r0 = blockIdx.x * 32, c0 = blockIdx.y * 32;
#pragma unroll
    for (int i = 0; i < 4; i++)
        tile[ty + i * 8][tx] = inp[(size_t)(r0 + ty + i * 8) * C + c0 + tx];
    __syncthreads();
#pragma unroll
    for (int i = 0; i < 4; i++)
        outp[(size_t)(c0 + ty + i * 8) * R + r0 + tx] =
            __float2bfloat16(tile[tx][ty + i * 8]);
}

// ---------------------------------------------------------------------------
// K1: gate. fp32 scores, top-2, softmax weights, per-expert row lists.
// Also writes bf16 copy of x. 16 rows/block (4 rows per wave), 256 threads.
// ---------------------------------------------------------------------------
__global__ __launch_bounds__(256) void gate_kernel(
    const float* __restrict__ x, const float* __restrict__ gate_w,
    const float* __restrict__ gate_b, bf16* __restrict__ x_bf16,
    int* __restrict__ rowlist, float* __restrict__ wlist, int* __restrict__ gcnt)
{
    __shared__ float gw[E_NUM][1024];  // 32 KB chunk of gate_w, transposed [e][d]
    __shared__ int   eidx[16][2];
    __shared__ float ew[16][2];
    __shared__ int   lcnt[E_NUM], gbase[E_NUM];

    int t = threadIdx.x;
    int w = t >> 6, l = t & 63;
    int rowblk = blockIdx.x * 16;
    int r0 = rowblk + w * 4;

    float acc[4][8];
#pragma unroll
    for (int j = 0; j < 4; j++)
#pragma unroll
        for (int ee = 0; ee < 8; ee++) acc[j][ee] = 0.0f;

    for (int c = 0; c < 3; c++) {
        int c0 = c * 1024;
        __syncthreads();
        // stage gate_w chunk: global [d][e] -> LDS [e][d]  (coalesced global reads)
#pragma unroll
        for (int i = 0; i < 32; i++) {
            int idx = i * 256 + t;                       // 0..8191
            gw[idx & 7][idx >> 3] = gate_w[(size_t)c0 * 8 + idx];
        }
        __syncthreads();
#pragma unroll
        for (int i = 0; i < 16; i++) {
            int dd = i * 64 + l;
            int dg = c0 + dd;
#pragma unroll
            for (int j = 0; j < 4; j++) {
                float xv = x[(size_t)(r0 + j) * D_DIM + dg];
                x_bf16[(size_t)(r0 + j) * D_DIM + dg] = __float2bfloat16(xv);
#pragma unroll
                for (int ee = 0; ee < 8; ee++)
                    acc[j][ee] += xv * gw[ee][dd];
            }
        }
    }

    // butterfly reduce each (row, expert) partial across the 64 lanes
#pragma unroll
    for (int j = 0; j < 4; j++)
#pragma unroll
        for (int ee = 0; ee < 8; ee++) {
            float v = acc[j][ee];
#pragma unroll
            for (int off = 1; off < 64; off <<= 1) v += __shfl_xor(v, off, 64);
            acc[j][ee] = v;
        }

    if (l == 0) {
        for (int j = 0; j < 4; j++) {
            float s[8];
#pragma unroll
            for (int ee = 0; ee < 8; ee++) s[ee] = acc[j][ee] + gate_b[ee];
            // top-1 / top-2, strict > keeps lowest index on ties (lax.top_k semantics)
            int i1 = 0; float m1 = s[0];
#pragma unroll
            for (int ee = 1; ee < 8; ee++) if (s[ee] > m1) { m1 = s[ee]; i1 = ee; }
            int i2 = -1; float m2 = -1e30f;
#pragma unroll
            for (int ee = 0; ee < 8; ee++)
                if (ee != i1 && s[ee] > m2) { m2 = s[ee]; i2 = ee; }
            float S = 0.0f;
#pragma unroll
            for (int ee = 0; ee < 8; ee++) S += __expf(s[ee] - m1) * 0.0f + expf(s[ee] - m1);
            float p1 = expf(s[i1] - m1) / S;
            float p2 = expf(m2 - m1) / S;
            float denom = p1 + p2 + 1e-8f;
            eidx[w * 4 + j][0] = i1; ew[w * 4 + j][0] = p1 / denom;
            eidx[w * 4 + j][1] = i2; ew[w * 4 + j][1] = p2 / denom;
        }
    }
    __syncthreads();
    if (t < 8) lcnt[t] = 0;
    __syncthreads();
    int my_e = -1, my_lp = -1, my_rl = -1, my_sl = -1;
    if (t < 32) {
        my_rl = t >> 1; my_sl = t & 1;
        my_e = eidx[my_rl][my_sl];
        my_lp = atomicAdd(&lcnt[my_e], 1);
    }
    __syncthreads();
    if (t < 8) gbase[t] = atomicAdd(&gcnt[t], lcnt[t]);
    __syncthreads();
    if (t < 32) {
        int pos = gbase[my_e] + my_lp;
        rowlist[my_e * B_ROWS + pos] = rowblk + my_rl;
        wlist[my_e * B_ROWS + pos]   = ew[my_rl][my_sl];
    }
}

// ---------------------------------------------------------------------------
// K2/K3a: per-expert GEMM  Out[m][n] = relu(A[m][:] . Bt[n][:] + bias[n]) (bf16)
// BM=64, BN=128, BK=64. 256 threads = 4 waves; wave tile 32x64 (2x4 16x16 MFMA).
// GATHER: A rows come from rowlist (x_bf16); else compact rows within expert.
// ---------------------------------------------------------------------------
template <bool GATHER>
__global__ __launch_bounds__(256) void gemm_kernel(
    const bf16* __restrict__ Asrc, int lda, int Kdim,
    const bf16* __restrict__ Bmat,      // [e][128][Kdim] bf16 (K-contiguous)
    const float* __restrict__ bias,     // [e][128]
    const int* __restrict__ rowlist, const int* __restrict__ gcnt,
    bf16* __restrict__ Out)             // [e][B_ROWS][128]
{
    int e = blockIdx.y;
    int cnt = gcnt[e];
    int t0 = blockIdx.x * 64;
    if (t0 >= cnt) return;
    int mcnt = cnt - t0; if (mcnt > 64) mcnt = 64;

    __shared__ bf16 Abuf[64][72];    // +8 pad breaks bank-conflict stride
    __shared__ bf16 Bbuf[128][72];
    __shared__ int  rows_s[64];

    int t = threadIdx.x;
    if (t < 64) {
        int rr = (t < mcnt) ? t : (mcnt - 1);
        rows_s[t] = GATHER ? rowlist[e * B_ROWS + t0 + rr] : (t0 + rr);
    }
    __syncthreads();

    const bf16* Abase = GATHER ? Asrc : (Asrc + (size_t)e * B_ROWS * H_DIM);
    const bf16* Bbase = Bmat + (size_t)e * H_DIM * Kdim;

    int w = t >> 6, l = t & 63;
    int mb = (w & 1) * 32, nb = (w >> 1) * 64;

    floatx4 acc[2][4];
#pragma unroll
    for (int mi = 0; mi < 2; mi++)
#pragma unroll
        for (int ni = 0; ni < 4; ni++) acc[mi][ni] = (floatx4){0.f, 0.f, 0.f, 0.f};

    // hoisted A-staging addresses: thread t stages 16B seg (t&7) of rows t>>3 and 32+(t>>3)
    int rA0 = rows_s[t >> 3];
    int rA1 = rows_s[32 + (t >> 3)];
    const bf16* aSrc0 = Abase + (size_t)rA0 * lda + (t & 7) * 8;
    const bf16* aSrc1 = Abase + (size_t)rA1 * lda + (t & 7) * 8;

    int nkb = Kdim >> 6;
    for (int kb = 0; kb < nkb; kb++) {
        int k0 = kb * 64;
        *(uint4*)&Abuf[t >> 3][(t & 7) * 8]        = *(const uint4*)(aSrc0 + k0);
        *(uint4*)&Abuf[32 + (t >> 3)][(t & 7) * 8] = *(const uint4*)(aSrc1 + k0);
#pragma unroll
        for (int i = 0; i < 4; i++) {
            int sidx = i * 256 + t;
            int n = sidx >> 3, sg = sidx & 7;
            *(uint4*)&Bbuf[n][sg * 8] =
                *(const uint4*)(Bbase + (size_t)n * Kdim + k0 + sg * 8);
        }
        __syncthreads();
#pragma unroll
        for (int kc = 0; kc < 64; kc += 32) {
            short8 af[2], bfr[4];
#pragma unroll
            for (int mi = 0; mi < 2; mi++)
                af[mi] = *(const short8*)&Abuf[mb + mi * 16 + (l & 15)][kc + (l >> 4) * 8];
#pragma unroll
            for (int ni = 0; ni < 4; ni++)
                bfr[ni] = *(const short8*)&Bbuf[nb + ni * 16 + (l & 15)][kc + (l >> 4) * 8];
#pragma unroll
            for (int mi = 0; mi < 2; mi++)
#pragma unroll
                for (int ni = 0; ni < 4; ni++)
                    acc[mi][ni] = __builtin_amdgcn_mfma_f32_16x16x32_bf16(
                        af[mi], bfr[ni], acc[mi][ni], 0, 0, 0);
        }
        __syncthreads();
    }

    // epilogue: D row = (l>>4)*4 + reg, col = l&15  (measured C/D layout)
#pragma unroll
    for (int mi = 0; mi < 2; mi++)
#pragma unroll
        for (int r = 0; r < 4; r++) {
            int row = mb + mi * 16 + (l >> 4) * 4 + r;
            if (row < mcnt) {
#pragma unroll
                for (int ni = 0; ni < 4; ni++) {
                    int col = nb + ni * 16 + (l & 15);
                    float v = acc[mi][ni][r] + bias[e * H_DIM + col];
                    v = fmaxf(v, 0.0f);
                    Out[(size_t)e * B_ROWS * H_DIM + (size_t)(t0 + row) * H_DIM + col] =
                        __float2bfloat16(v);
                }
            }
        }
}

// ---------------------------------------------------------------------------
// K3b: out = h2 @ w3 + b3 ; y[row] += weight * out  (fp32, atomic)
// one wave per entry-row; lane l holds h2[l], h2[l+64]
// ---------------------------------------------------------------------------
__global__ __launch_bounds__(256) void combine_kernel(
    const bf16* __restrict__ h2buf, const float* __restrict__ w3,
    const float* __restrict__ b3, const int* __restrict__ rowlist,
    const float* __restrict__ wlist, const int* __restrict__ gcnt,
    float* __restrict__ y)
{
    int e = blockIdx.y;
    int cnt = gcnt[e];
    int t0 = blockIdx.x * 64;
    if (t0 >= cnt) return;
    int mcnt = cnt - t0; if (mcnt > 64) mcnt = 64;

    __shared__ float w3s[H_DIM][11];  // pad 10->11: odd stride kills bank conflicts
    __shared__ float b3s[O_DIM];
    int t = threadIdx.x;
    for (int idx = t; idx < H_DIM * O_DIM; idx += 256)
        w3s[idx / O_DIM][idx % O_DIM] = w3[(size_t)e * H_DIM * O_DIM + idx];
    if (t < O_DIM) b3s[t] = b3[e * O_DIM + t];
    __syncthreads();

    int w = t >> 6, l = t & 63;
    for (int ii = w; ii < mcnt; ii += 4) {
        int gpos = t0 + ii;
        const bf16* h2r = h2buf + (size_t)e * B_ROWS * H_DIM + (size_t)gpos * H_DIM;
        float ha = __bfloat162float(h2r[l]);
        float hb = __bfloat162float(h2r[l + 64]);
        float p[O_DIM];
#pragma unroll
        for (int o = 0; o < O_DIM; o++)
            p[o] = ha * w3s[l][o] + hb * w3s[l + 64][o];
#pragma unroll
        for (int o = 0; o < O_DIM; o++)
#pragma unroll
            for (int off = 1; off < 64; off <<= 1)
                p[o] += __shfl_xor(p[o], off, 64);
        if (l == 0) {
            int row = rowlist[e * B_ROWS + gpos];
            float wt = wlist[e * B_ROWS + gpos];
#pragma unroll
            for (int o = 0; o < O_DIM; o++)
                atomicAdd(&y[(size_t)row * O_DIM + o], wt * (p[o] + b3s[o]));
        }
    }
}

// ---------------------------------------------------------------------------
extern "C" void kernel_launch(void* const* d_in, const int* in_sizes, int n_in,
                              void* d_out, int out_size, void* d_ws, size_t ws_size,
                              hipStream_t stream) {
    (void)in_sizes; (void)n_in; (void)ws_size;
    const float* x      = (const float*)d_in[0];
    const float* gate_w = (const float*)d_in[1];
    const float* gate_b = (const float*)d_in[2];
    const float* w1     = (const float*)d_in[3];
    const float* b1     = (const float*)d_in[4];
    const float* w2     = (const float*)d_in[5];
    const float* b2     = (const float*)d_in[6];
    const float* w3     = (const float*)d_in[7];
    const float* b3     = (const float*)d_in[8];
    float* y = (float*)d_out;

    char* ws = (char*)d_ws;
    size_t off = 0;
    auto alloc = [&](size_t bytes) {
        void* p = ws + off;
        off = (off + bytes + 255) & ~(size_t)255;
        return p;
    };
    bf16*  x_bf16  = (bf16*)alloc((size_t)B_ROWS * D_DIM * 2);            // 100.7 MB
    bf16*  w1t     = (bf16*)alloc((size_t)E_NUM * H_DIM * D_DIM * 2);     // 6.3 MB
    bf16*  h1buf   = (bf16*)alloc((size_t)E_NUM * B_ROWS * H_DIM * 2);    // 33.6 MB
    int*   rowlist = (int*)alloc((size_t)E_NUM * B_ROWS * 4);
    float* wlist   = (float*)alloc((size_t)E_NUM * B_ROWS * 4);
    int*   gcnt    = (int*)alloc(64);
    bf16*  w2t     = (bf16*)alloc((size_t)E_NUM * H_DIM * H_DIM * 2);
    bf16*  h2buf   = x_bf16;  // alias: x_bf16 is dead after the gather GEMM

    hipMemsetAsync(d_out, 0, (size_t)out_size * sizeof(float), stream);
    hipMemsetAsync(gcnt, 0, 64, stream);

    transpose_bf16_kernel<<<dim3(D_DIM / 32, H_DIM / 32, E_NUM), dim3(32, 8), 0, stream>>>(
        w1, w1t, D_DIM, H_DIM);
    transpose_bf16_kernel<<<dim3(H_DIM / 32, H_DIM / 32, E_NUM), dim3(32, 8), 0, stream>>>(
        w2, w2t, H_DIM, H_DIM);
    gate_kernel<<<B_ROWS / 16, 256, 0, stream>>>(x, gate_w, gate_b, x_bf16,
                                                 rowlist, wlist, gcnt);
    gemm_kernel<true><<<dim3(B_ROWS / 64, E_NUM), 256, 0, stream>>>(
        x_bf16, D_DIM, D_DIM, w1t, b1, rowlist, gcnt, h1buf);
    gemm_kernel<false><<<dim3(B_ROWS / 64, E_NUM), 256, 0, stream>>>(
        h1buf, H_DIM, H_DIM, w2t, b2, rowlist, gcnt, h2buf);
    combine_kernel<<<dim3(B_ROWS / 64, E_NUM), 256, 0, stream>>>(
        h2buf, w3, b3, rowlist, wlist, gcnt, y);
}

// Round 2
// 566.543 us; speedup vs baseline: 1.0862x; 1.0862x over previous
//
#include <hip/hip_runtime.h>
#include <hip/hip_bf16.h>

#define B_ROWS 16384
#define D_DIM  3072
#define H_DIM  128
#define O_DIM  10
#define E_NUM  8

typedef __hip_bfloat16 bf16;
typedef __attribute__((ext_vector_type(8))) short short8;   // 8 bf16 = 4 VGPRs (MFMA A/B frag)
typedef __attribute__((ext_vector_type(4))) float floatx4;  // MFMA C/D frag

// ---------------------------------------------------------------------------
// K0: transpose+convert  in[e][R][C] fp32  ->  out[e][C][R] bf16
// ---------------------------------------------------------------------------
__global__ void transpose_bf16_kernel(const float* __restrict__ in,
                                      bf16* __restrict__ out, int R, int C) {
    int e = blockIdx.z;
    const float* inp = in + (size_t)e * R * C;
    bf16* outp = out + (size_t)e * R * C;
    __shared__ float tile[32][33];
    int tx = threadIdx.x;   // 0..31
    int ty = threadIdx.y;   // 0..7
    int r0 = blockIdx.x * 32, c0 = blockIdx.y * 32;
#pragma unroll
    for (int i = 0; i < 4; i++)
        tile[ty + i * 8][tx] = inp[(size_t)(r0 + ty + i * 8) * C + c0 + tx];
    __syncthreads();
#pragma unroll
    for (int i = 0; i < 4; i++)
        outp[(size_t)(c0 + ty + i * 8) * R + r0 + tx] =
            __float2bfloat16(tile[tx][ty + i * 8]);
}

// ---------------------------------------------------------------------------
// K1: gate v2. 32 rows/block (8 per wave), float4 x loads, uint2 bf16 stores,
// gate_w chunk in LDS read once per 8 rows into registers. fp32 throughout.
// ---------------------------------------------------------------------------
__global__ __launch_bounds__(256) void gate_kernel(
    const float* __restrict__ x, const float* __restrict__ gate_w,
    const float* __restrict__ gate_b, bf16* __restrict__ x_bf16,
    int* __restrict__ rowlist, float* __restrict__ wlist, int* __restrict__ gcnt)
{
    __shared__ float gws[E_NUM][1032];   // [e][d-in-chunk], pad to 1032
    __shared__ int   eidx[32][2];
    __shared__ float ew[32][2];
    __shared__ int   lcnt[E_NUM], gbase[E_NUM];

    int t = threadIdx.x, w = t >> 6, l = t & 63;
    int rowblk = blockIdx.x * 32;
    int r0 = rowblk + w * 8;

    float acc[8][8];
#pragma unroll
    for (int r = 0; r < 8; r++)
#pragma unroll
        for (int e = 0; e < 8; e++) acc[r][e] = 0.0f;

    for (int c = 0; c < 3; c++) {
        __syncthreads();
        // stage gate_w chunk: global [d][e] -> LDS [e][d] (coalesced reads)
#pragma unroll
        for (int i = 0; i < 32; i++) {
            int idx = i * 256 + t;                 // 0..8191
            gws[idx & 7][idx >> 3] = gate_w[c * 8192 + idx];
        }
        __syncthreads();
#pragma unroll
        for (int j = 0; j < 4; j++) {
            int dd = j * 256 + l * 4;              // 4 consecutive d per lane
            float4 g0[8];
#pragma unroll
            for (int e = 0; e < 8; e++)
                g0[e] = *(const float4*)&gws[e][dd];
#pragma unroll
            for (int r = 0; r < 8; r++) {
                size_t xi = (size_t)(r0 + r) * D_DIM + c * 1024 + dd;
                float4 xv = *(const float4*)&x[xi];
                union { bf16 h[4]; uint2 v; } pk;
                pk.h[0] = __float2bfloat16(xv.x);
                pk.h[1] = __float2bfloat16(xv.y);
                pk.h[2] = __float2bfloat16(xv.z);
                pk.h[3] = __float2bfloat16(xv.w);
                *(uint2*)&x_bf16[xi] = pk.v;
#pragma unroll
                for (int e = 0; e < 8; e++)
                    acc[r][e] += xv.x * g0[e].x + xv.y * g0[e].y +
                                 xv.z * g0[e].z + xv.w * g0[e].w;
            }
        }
    }

    // butterfly reduce each (row, expert) partial across the 64 lanes
#pragma unroll
    for (int r = 0; r < 8; r++)
#pragma unroll
        for (int e = 0; e < 8; e++) {
            float v = acc[r][e];
#pragma unroll
            for (int off = 1; off < 64; off <<= 1) v += __shfl_xor(v, off, 64);
            acc[r][e] = v;
        }

    if (l == 0) {
#pragma unroll
        for (int r = 0; r < 8; r++) {
            float s[8];
#pragma unroll
            for (int e = 0; e < 8; e++) s[e] = acc[r][e] + gate_b[e];
            // top-1 / top-2, strict > keeps lowest index on ties (lax.top_k)
            int i1 = 0; float m1 = s[0];
#pragma unroll
            for (int e = 1; e < 8; e++) if (s[e] > m1) { m1 = s[e]; i1 = e; }
            int i2 = -1; float m2 = -1e30f;
#pragma unroll
            for (int e = 0; e < 8; e++)
                if (e != i1 && s[e] > m2) { m2 = s[e]; i2 = e; }
            float S = 0.0f;
#pragma unroll
            for (int e = 0; e < 8; e++) S += expf(s[e] - m1);
            float p1 = expf(s[i1] - m1) / S;
            float p2 = expf(m2 - m1) / S;
            float denom = p1 + p2 + 1e-8f;
            eidx[w * 8 + r][0] = i1; ew[w * 8 + r][0] = p1 / denom;
            eidx[w * 8 + r][1] = i2; ew[w * 8 + r][1] = p2 / denom;
        }
    }
    __syncthreads();
    if (t < 8) lcnt[t] = 0;
    __syncthreads();
    int my_e = 0, my_lp = 0, my_rl = 0, my_sl = 0;
    if (t < 64) {
        my_rl = t >> 1; my_sl = t & 1;
        my_e = eidx[my_rl][my_sl];
        my_lp = atomicAdd(&lcnt[my_e], 1);
    }
    __syncthreads();
    if (t < 8) gbase[t] = atomicAdd(&gcnt[t], lcnt[t]);
    __syncthreads();
    if (t < 64) {
        int pos = gbase[my_e] + my_lp;
        rowlist[my_e * B_ROWS + pos] = rowblk + my_rl;
        wlist[my_e * B_ROWS + pos]   = ew[my_rl][my_sl];
    }
}

// ---------------------------------------------------------------------------
// K2/K3: per-expert GEMM, 512 threads = 8 waves, tile BM=64 BN=128 BK=64.
// Wave-tile 16x64 (1x4 16x16x32 MFMA) -> 16 waves/CU at 2 blocks/CU.
// Register double-buffer: kb+1 global loads issued before kb compute.
// FUSE: second GEMM keeps h2 tile in LDS and applies w3/b3 + weighted
// atomic scatter into y, skipping the h2buf round-trip.
// ---------------------------------------------------------------------------
template <bool GATHER, bool FUSE>
__global__ __launch_bounds__(512) void gemm8_kernel(
    const bf16* __restrict__ Asrc, int lda, int Kdim,
    const bf16* __restrict__ Bmat,      // [e][128][Kdim] bf16 (K-contiguous)
    const float* __restrict__ bias,     // [e][128]
    const int* __restrict__ rowlist, const float* __restrict__ wlist,
    const int* __restrict__ gcnt,
    bf16* __restrict__ Out,             // [e][B_ROWS][128] (compacted rows)
    const float* __restrict__ w3, const float* __restrict__ b3,
    float* __restrict__ y)
{
    int e = blockIdx.y;
    int cnt = gcnt[e];
    int t0 = blockIdx.x * 64;
    if (t0 >= cnt) return;
    int mcnt = cnt - t0; if (mcnt > 64) mcnt = 64;

    __shared__ bf16 Abuf[64][72];    // +8 pad breaks worst bank conflicts
    __shared__ bf16 Bbuf[128][72];
    __shared__ int  rows_s[64];
    __shared__ float w3s[H_DIM][11]; // odd stride: conflict-free
    __shared__ float b3s[16];

    int t = threadIdx.x, w = t >> 6, l = t & 63;

    if (t < 64) {
        int rr = (t < mcnt) ? t : (mcnt - 1);
        rows_s[t] = GATHER ? rowlist[e * B_ROWS + t0 + rr] : (t0 + rr);
    }
    if constexpr (FUSE) {
        for (int idx = t; idx < H_DIM * O_DIM; idx += 512)
            w3s[idx / O_DIM][idx % O_DIM] = w3[(size_t)e * H_DIM * O_DIM + idx];
        if (t < O_DIM) b3s[t] = b3[e * O_DIM + t];
    }
    __syncthreads();

    const bf16* Abase = GATHER ? Asrc : (Asrc + (size_t)e * B_ROWS * H_DIM);
    const bf16* Bbase = Bmat + (size_t)e * H_DIM * Kdim;

    // staging: thread t stages A row t>>3 seg t&7 (1x16B), B rows t>>3 and
    // 64+(t>>3) seg t&7 (2x16B).
    const bf16* aSrc  = Abase + (size_t)rows_s[t >> 3] * lda + (t & 7) * 8;
    const bf16* bSrc0 = Bbase + (size_t)(t >> 3) * Kdim + (t & 7) * 8;
    const bf16* bSrc1 = bSrc0 + (size_t)64 * Kdim;
    bf16* aDst  = &Abuf[t >> 3][(t & 7) * 8];
    bf16* bDst0 = &Bbuf[t >> 3][(t & 7) * 8];
    bf16* bDst1 = &Bbuf[64 + (t >> 3)][(t & 7) * 8];

    uint4 pa  = *(const uint4*)aSrc;
    uint4 pb0 = *(const uint4*)bSrc0;
    uint4 pb1 = *(const uint4*)bSrc1;

    int mb = (w & 3) * 16, nb = (w >> 2) * 64;

    floatx4 acc[4];
#pragma unroll
    for (int ni = 0; ni < 4; ni++) acc[ni] = (floatx4){0.f, 0.f, 0.f, 0.f};

    int nkb = Kdim >> 6;
    for (int kb = 0; kb < nkb; kb++) {
        __syncthreads();                 // previous compute done with LDS
        *(uint4*)aDst  = pa;
        *(uint4*)bDst0 = pb0;
        *(uint4*)bDst1 = pb1;
        __syncthreads();
        if (kb + 1 < nkb) {              // prefetch kb+1 during kb compute
            int k0 = (kb + 1) * 64;
            pa  = *(const uint4*)(aSrc + k0);
            pb0 = *(const uint4*)(bSrc0 + k0);
            pb1 = *(const uint4*)(bSrc1 + k0);
        }
#pragma unroll
        for (int kc = 0; kc < 64; kc += 32) {
            short8 af = *(const short8*)&Abuf[mb + (l & 15)][kc + (l >> 4) * 8];
            short8 bfr[4];
#pragma unroll
            for (int ni = 0; ni < 4; ni++)
                bfr[ni] = *(const short8*)&Bbuf[nb + ni * 16 + (l & 15)][kc + (l >> 4) * 8];
#pragma unroll
            for (int ni = 0; ni < 4; ni++)
                acc[ni] = __builtin_amdgcn_mfma_f32_16x16x32_bf16(af, bfr[ni], acc[ni], 0, 0, 0);
        }
    }

    // epilogue: D row = (l>>4)*4 + reg, col = l&15 (measured C/D layout)
    if constexpr (!FUSE) {
#pragma unroll
        for (int r = 0; r < 4; r++) {
            int row = mb + (l >> 4) * 4 + r;
            if (row < mcnt) {
#pragma unroll
                for (int ni = 0; ni < 4; ni++) {
                    int col = nb + ni * 16 + (l & 15);
                    float v = fmaxf(acc[ni][r] + bias[e * H_DIM + col], 0.0f);
                    Out[(size_t)e * B_ROWS * H_DIM + (size_t)(t0 + row) * H_DIM + col] =
                        __float2bfloat16(v);
                }
            }
        }
    } else {
        __syncthreads();                 // done reading Bbuf; reuse as h2 tile
        bf16* h2s = &Bbuf[0][0];         // [64][132] bf16 (8448 <= 9216 elems)
#pragma unroll
        for (int r = 0; r < 4; r++) {
            int row = mb + (l >> 4) * 4 + r;
#pragma unroll
            for (int ni = 0; ni < 4; ni++) {
                int col = nb + ni * 16 + (l & 15);
                float v = fmaxf(acc[ni][r] + bias[e * H_DIM + col], 0.0f);
                h2s[row * 132 + col] = __float2bfloat16(v);
            }
        }
        __syncthreads();
        // combine: wave w handles rows w*8 .. w*8+7; lane l holds cols l, l+64
#pragma unroll
        for (int rr = 0; rr < 8; rr++) {
            int ii = w * 8 + rr;
            if (ii < mcnt) {
                float ha = __bfloat162float(h2s[ii * 132 + l]);
                float hb = __bfloat162float(h2s[ii * 132 + 64 + l]);
                float p[O_DIM];
#pragma unroll
                for (int o = 0; o < O_DIM; o++)
                    p[o] = ha * w3s[l][o] + hb * w3s[l + 64][o];
#pragma unroll
                for (int o = 0; o < O_DIM; o++)
#pragma unroll
                    for (int off = 1; off < 64; off <<= 1)
                        p[o] += __shfl_xor(p[o], off, 64);
                if (l == 0) {
                    int gpos = t0 + ii;
                    int row = rowlist[e * B_ROWS + gpos];
                    float wt = wlist[e * B_ROWS + gpos];
#pragma unroll
                    for (int o = 0; o < O_DIM; o++)
                        atomicAdd(&y[(size_t)row * O_DIM + o], wt * (p[o] + b3s[o]));
                }
            }
        }
    }
}

// ---------------------------------------------------------------------------
extern "C" void kernel_launch(void* const* d_in, const int* in_sizes, int n_in,
                              void* d_out, int out_size, void* d_ws, size_t ws_size,
                              hipStream_t stream) {
    (void)in_sizes; (void)n_in; (void)ws_size;
    const float* x      = (const float*)d_in[0];
    const float* gate_w = (const float*)d_in[1];
    const float* gate_b = (const float*)d_in[2];
    const float* w1     = (const float*)d_in[3];
    const float* b1     = (const float*)d_in[4];
    const float* w2     = (const float*)d_in[5];
    const float* b2     = (const float*)d_in[6];
    const float* w3     = (const float*)d_in[7];
    const float* b3     = (const float*)d_in[8];
    float* y = (float*)d_out;

    char* ws = (char*)d_ws;
    size_t off = 0;
    auto alloc = [&](size_t bytes) {
        void* p = ws + off;
        off = (off + bytes + 255) & ~(size_t)255;
        return p;
    };
    bf16*  x_bf16  = (bf16*)alloc((size_t)B_ROWS * D_DIM * 2);            // 100.7 MB
    bf16*  w1t     = (bf16*)alloc((size_t)E_NUM * H_DIM * D_DIM * 2);     // 6.3 MB
    bf16*  h1buf   = (bf16*)alloc((size_t)E_NUM * B_ROWS * H_DIM * 2);    // 33.6 MB
    int*   rowlist = (int*)alloc((size_t)E_NUM * B_ROWS * 4);
    float* wlist   = (float*)alloc((size_t)E_NUM * B_ROWS * 4);
    int*   gcnt    = (int*)alloc(64);
    bf16*  w2t     = (bf16*)alloc((size_t)E_NUM * H_DIM * H_DIM * 2);

    hipMemsetAsync(d_out, 0, (size_t)out_size * sizeof(float), stream);
    hipMemsetAsync(gcnt, 0, 64, stream);

    transpose_bf16_kernel<<<dim3(D_DIM / 32, H_DIM / 32, E_NUM), dim3(32, 8), 0, stream>>>(
        w1, w1t, D_DIM, H_DIM);
    transpose_bf16_kernel<<<dim3(H_DIM / 32, H_DIM / 32, E_NUM), dim3(32, 8), 0, stream>>>(
        w2, w2t, H_DIM, H_DIM);
    gate_kernel<<<B_ROWS / 32, 256, 0, stream>>>(x, gate_w, gate_b, x_bf16,
                                                 rowlist, wlist, gcnt);
    // h1 = relu(x_gathered @ w1 + b1)
    gemm8_kernel<true, false><<<dim3(B_ROWS / 64, E_NUM), 512, 0, stream>>>(
        x_bf16, D_DIM, D_DIM, w1t, b1, rowlist, wlist, gcnt, h1buf,
        nullptr, nullptr, nullptr);
    // h2 = relu(h1 @ w2 + b2); y += weight * (h2 @ w3 + b3)   (fused)
    gemm8_kernel<false, true><<<dim3(B_ROWS / 64, E_NUM), 512, 0, stream>>>(
        h1buf, H_DIM, H_DIM, w2t, b2, rowlist, wlist, gcnt, h1buf,
        w3, b3, y);
}

// Round 4
// 550.330 us; speedup vs baseline: 1.1182x; 1.0295x over previous
//
#include <hip/hip_runtime.h>
#include <hip/hip_bf16.h>

#define B_ROWS 16384
#define D_DIM  3072
#define H_DIM  128
#define O_DIM  10
#define E_NUM  8

typedef __hip_bfloat16 bf16;
typedef __attribute__((ext_vector_type(8))) short short8;   // 8 bf16 = 4 VGPRs (MFMA A/B frag)
typedef __attribute__((ext_vector_type(4))) float floatx4;  // MFMA C/D frag

// ---------------------------------------------------------------------------
// K0: transpose+convert  in[e][R][C] fp32  ->  out[e][C][R] bf16
// ---------------------------------------------------------------------------
__global__ void transpose_bf16_kernel(const float* __restrict__ in,
                                      bf16* __restrict__ out, int R, int C) {
    int e = blockIdx.z;
    const float* inp = in + (size_t)e * R * C;
    bf16* outp = out + (size_t)e * R * C;
    __shared__ float tile[32][33];
    int tx = threadIdx.x;   // 0..31
    int ty = threadIdx.y;   // 0..7
    int r0 = blockIdx.x * 32, c0 = blockIdx.y * 32;
#pragma unroll
    for (int i = 0; i < 4; i++)
        tile[ty + i * 8][tx] = inp[(size_t)(r0 + ty + i * 8) * C + c0 + tx];
    __syncthreads();
#pragma unroll
    for (int i = 0; i < 4; i++)
        outp[(size_t)(c0 + ty + i * 8) * R + r0 + tx] =
            __float2bfloat16(tile[tx][ty + i * 8]);
}

// ---------------------------------------------------------------------------
// K1: gate v3. 16 rows/block (4 per wave) -> acc[4][8]=32 VGPRs, 1024 blocks.
// fp32 math (top-k selection needs fp32 scores). Also emits x as bf16.
// ---------------------------------------------------------------------------
__global__ __launch_bounds__(256, 3) void gate_kernel(
    const float* __restrict__ x, const float* __restrict__ gate_w,
    const float* __restrict__ gate_b, bf16* __restrict__ x_bf16,
    int* __restrict__ rowlist, float* __restrict__ wlist, int* __restrict__ gcnt)
{
    __shared__ float gws[E_NUM][1036];   // pad 1036: conflict-free stores, 16B-aligned
    __shared__ int   eidx[16][2];
    __shared__ float ew[16][2];
    __shared__ int   lcnt[E_NUM], gbase[E_NUM];

    int t = threadIdx.x, w = t >> 6, l = t & 63;
    int rowblk = blockIdx.x * 16;
    int r0 = rowblk + w * 4;

    float acc[4][8];
#pragma unroll
    for (int r = 0; r < 4; r++)
#pragma unroll
        for (int e = 0; e < 8; e++) acc[r][e] = 0.0f;

    for (int c = 0; c < 3; c++) {
        __syncthreads();
        // stage gate_w chunk: global [d][e] -> LDS [e][d] (coalesced reads)
#pragma unroll
        for (int i = 0; i < 32; i++) {
            int idx = i * 256 + t;                 // 0..8191
            gws[idx & 7][idx >> 3] = gate_w[c * 8192 + idx];
        }
        __syncthreads();
#pragma unroll
        for (int j = 0; j < 4; j++) {
            int dd = j * 256 + l * 4;              // 4 consecutive d per lane
            float4 g0[8];
#pragma unroll
            for (int e = 0; e < 8; e++)
                g0[e] = *(const float4*)&gws[e][dd];
            float4 xv[4];
#pragma unroll
            for (int r = 0; r < 4; r++)
                xv[r] = *(const float4*)&x[(size_t)(r0 + r) * D_DIM + c * 1024 + dd];
#pragma unroll
            for (int r = 0; r < 4; r++) {
                union { bf16 h[4]; uint2 v; } pk;
                pk.h[0] = __float2bfloat16(xv[r].x);
                pk.h[1] = __float2bfloat16(xv[r].y);
                pk.h[2] = __float2bfloat16(xv[r].z);
                pk.h[3] = __float2bfloat16(xv[r].w);
                *(uint2*)&x_bf16[(size_t)(r0 + r) * D_DIM + c * 1024 + dd] = pk.v;
            }
#pragma unroll
            for (int r = 0; r < 4; r++)
#pragma unroll
                for (int e = 0; e < 8; e++)
                    acc[r][e] += xv[r].x * g0[e].x + xv[r].y * g0[e].y +
                                 xv[r].z * g0[e].z + xv[r].w * g0[e].w;
        }
    }

    // butterfly reduce each (row, expert) partial across the 64 lanes
#pragma unroll
    for (int r = 0; r < 4; r++)
#pragma unroll
        for (int e = 0; e < 8; e++) {
            float v = acc[r][e];
#pragma unroll
            for (int off = 1; off < 64; off <<= 1) v += __shfl_xor(v, off, 64);
            acc[r][e] = v;
        }

    if (l == 0) {
#pragma unroll
        for (int r = 0; r < 4; r++) {
            float s[8];
#pragma unroll
            for (int e = 0; e < 8; e++) s[e] = acc[r][e] + gate_b[e];
            // top-1 / top-2, strict > keeps lowest index on ties (lax.top_k)
            int i1 = 0; float m1 = s[0];
#pragma unroll
            for (int e = 1; e < 8; e++) if (s[e] > m1) { m1 = s[e]; i1 = e; }
            int i2 = -1; float m2 = -1e30f;
#pragma unroll
            for (int e = 0; e < 8; e++)
                if (e != i1 && s[e] > m2) { m2 = s[e]; i2 = e; }
            float S = 0.0f;
#pragma unroll
            for (int e = 0; e < 8; e++) S += expf(s[e] - m1);
            float p1 = expf(s[i1] - m1) / S;
            float p2 = expf(m2 - m1) / S;
            float denom = p1 + p2 + 1e-8f;
            eidx[w * 4 + r][0] = i1; ew[w * 4 + r][0] = p1 / denom;
            eidx[w * 4 + r][1] = i2; ew[w * 4 + r][1] = p2 / denom;
        }
    }
    __syncthreads();
    if (t < 8) lcnt[t] = 0;
    __syncthreads();
    int my_e = 0, my_lp = 0, my_rl = 0, my_sl = 0;
    if (t < 32) {
        my_rl = t >> 1; my_sl = t & 1;
        my_e = eidx[my_rl][my_sl];
        my_lp = atomicAdd(&lcnt[my_e], 1);
    }
    __syncthreads();
    if (t < 8) gbase[t] = atomicAdd(&gcnt[t], lcnt[t]);
    __syncthreads();
    if (t < 32) {
        int pos = gbase[my_e] + my_lp;
        rowlist[my_e * B_ROWS + pos] = rowblk + my_rl;
        wlist[my_e * B_ROWS + pos]   = ew[my_rl][my_sl];
    }
}

// ---------------------------------------------------------------------------
// K2: fully-fused expert kernel. 64 gathered rows per block, 4 waves.
//  phase 1: h1 = relu(x @ w1 + b1)   BM=64 BN=128 BK=64, dbuf LDS, 1 barrier
//  phase 2: h2 = relu(h1 @ w2 + b2)  h1 in LDS, w2 staged once (K=128)
//  phase 3: ytile = h2 @ w3t + b3    MFMA vs zero-padded 16x128 w3t
//  scatter: y[row] += weight * ytile (atomic, 2 contributions per row total)
// ---------------------------------------------------------------------------
__global__ __launch_bounds__(256, 2) void expert_kernel(
    const bf16* __restrict__ xb,        // [B][D] bf16
    const bf16* __restrict__ w1t,       // [E][H][D] (n-major, k-contig)
    const float* __restrict__ b1,       // [E][H]
    const bf16* __restrict__ w2t,       // [E][H][H] (n-major, k-contig)
    const float* __restrict__ b2,       // [E][H]
    const float* __restrict__ w3,       // [E][H][O]
    const float* __restrict__ b3,       // [E][O]
    const int* __restrict__ rowlist, const float* __restrict__ wlist,
    const int* __restrict__ gcnt, float* __restrict__ y)
{
    int e = blockIdx.y;
    int cnt = gcnt[e];
    int t0 = blockIdx.x * 64;
    if (t0 >= cnt) return;
    int mcnt = cnt - t0; if (mcnt > 64) mcnt = 64;

    // big aliased region: phase1 = Ab[2][64][72] + Bb[2][128][72] bf16 (55296 B)
    //                     phase2 = h1s[64][136] (17408 B) + w2s[128][136] (34816 B)
    //                     phase3 = h2s aliases h1s
    __shared__ __align__(16) char BIG[55296];
    __shared__ __align__(16) bf16 w3ts[16 * 136];
    __shared__ float b1s[H_DIM], b2s[H_DIM], b3s[16], wts[64];
    __shared__ int rows_s[64];

    int t = threadIdx.x, w = t >> 6, l = t & 63;

    if (t < 64) {
        int rr = (t < mcnt) ? t : (mcnt - 1);
        rows_s[t] = rowlist[e * B_ROWS + t0 + rr];
        wts[t]    = wlist[e * B_ROWS + t0 + rr];
    }
    if (t < H_DIM) { b1s[t] = b1[e * H_DIM + t]; b2s[t] = b2[e * H_DIM + t]; }
    if (t < O_DIM) b3s[t] = b3[e * O_DIM + t];
    // w3t staging: w3ts[o][h] = w3[e][h][o], rows 10..15 zero
    for (int idx = t; idx < H_DIM * O_DIM; idx += 256)
        w3ts[(idx % 10) * 136 + idx / 10] = __float2bfloat16(w3[(size_t)e * H_DIM * O_DIM + idx]);
    for (int idx = t; idx < 6 * 128; idx += 256)
        w3ts[(10 + idx / 128) * 136 + (idx % 128)] = __float2bfloat16(0.0f);
    __syncthreads();

    const bf16* Bbase = w1t + (size_t)e * H_DIM * D_DIM;
    int row_a = t >> 3, off8 = (t & 7) * 8;
    const bf16* aS0 = xb + (size_t)rows_s[row_a] * D_DIM + off8;
    const bf16* aS1 = xb + (size_t)rows_s[32 + row_a] * D_DIM + off8;
    const bf16* bS0 = Bbase + (size_t)row_a * D_DIM + off8;
    const bf16* bS1 = Bbase + (size_t)(32 + row_a) * D_DIM + off8;
    const bf16* bS2 = Bbase + (size_t)(64 + row_a) * D_DIM + off8;
    const bf16* bS3 = Bbase + (size_t)(96 + row_a) * D_DIM + off8;

    uint4 ra0 = *(const uint4*)aS0, ra1 = *(const uint4*)aS1;
    uint4 rb0 = *(const uint4*)bS0, rb1 = *(const uint4*)bS1;
    uint4 rb2 = *(const uint4*)bS2, rb3 = *(const uint4*)bS3;

    int mb = (w & 1) * 32, nb = (w >> 1) * 64;

    floatx4 acc[2][4];
#pragma unroll
    for (int mi = 0; mi < 2; mi++)
#pragma unroll
        for (int ni = 0; ni < 4; ni++) acc[mi][ni] = (floatx4){0.f, 0.f, 0.f, 0.f};

    const int NKB = D_DIM / 64;   // 48
    for (int kb = 0; kb < NKB; kb++) {
        bf16* A  = (bf16*)(BIG + (kb & 1) * 9216);
        bf16* Bb = (bf16*)(BIG + 18432 + (kb & 1) * 18432);
        *(uint4*)&A[row_a * 72 + off8]         = ra0;
        *(uint4*)&A[(32 + row_a) * 72 + off8]  = ra1;
        *(uint4*)&Bb[row_a * 72 + off8]        = rb0;
        *(uint4*)&Bb[(32 + row_a) * 72 + off8] = rb1;
        *(uint4*)&Bb[(64 + row_a) * 72 + off8] = rb2;
        *(uint4*)&Bb[(96 + row_a) * 72 + off8] = rb3;
        __syncthreads();
        if (kb + 1 < NKB) {                    // prefetch overlaps MFMA below
            int k0 = (kb + 1) * 64;
            ra0 = *(const uint4*)(aS0 + k0); ra1 = *(const uint4*)(aS1 + k0);
            rb0 = *(const uint4*)(bS0 + k0); rb1 = *(const uint4*)(bS1 + k0);
            rb2 = *(const uint4*)(bS2 + k0); rb3 = *(const uint4*)(bS3 + k0);
        }
#pragma unroll
        for (int kc = 0; kc < 64; kc += 32) {
            short8 af[2], bfr[4];
#pragma unroll
            for (int mi = 0; mi < 2; mi++)
                af[mi] = *(const short8*)&A[(mb + mi * 16 + (l & 15)) * 72 + kc + (l >> 4) * 8];
#pragma unroll
            for (int ni = 0; ni < 4; ni++)
                bfr[ni] = *(const short8*)&Bb[(nb + ni * 16 + (l & 15)) * 72 + kc + (l >> 4) * 8];
#pragma unroll
            for (int mi = 0; mi < 2; mi++)
#pragma unroll
                for (int ni = 0; ni < 4; ni++)
                    acc[mi][ni] = __builtin_amdgcn_mfma_f32_16x16x32_bf16(
                        af[mi], bfr[ni], acc[mi][ni], 0, 0, 0);
        }
    }
    __syncthreads();   // all waves done with last compute before BIG is reused

    // phase 2 setup: h1s[64][136] = relu(h1+b1); stage w2s[128][136]
    bf16* h1s = (bf16*)BIG;
    bf16* w2s = (bf16*)(BIG + 17408);
#pragma unroll
    for (int mi = 0; mi < 2; mi++)
#pragma unroll
        for (int r = 0; r < 4; r++) {
            int row = mb + mi * 16 + (l >> 4) * 4 + r;
#pragma unroll
            for (int ni = 0; ni < 4; ni++) {
                int col = nb + ni * 16 + (l & 15);
                float v = fmaxf(acc[mi][ni][r] + b1s[col], 0.0f);
                h1s[row * 136 + col] = __float2bfloat16(v);
            }
        }
    {
        const bf16* w2base = w2t + (size_t)e * H_DIM * H_DIM;
#pragma unroll
        for (int k = 0; k < 8; k++) {
            int si = t + 256 * k;               // 0..2047 = 128 rows x 16 chunks
            int rr = si >> 4, oo = (si & 15) * 8;
            *(uint4*)&w2s[rr * 136 + oo] = *(const uint4*)(w2base + (size_t)rr * H_DIM + oo);
        }
    }
    __syncthreads();

    // phase 2 MFMA: h2 = relu(h1s @ w2s + b2), K=128
    floatx4 acc2[2][4];
#pragma unroll
    for (int mi = 0; mi < 2; mi++)
#pragma unroll
        for (int ni = 0; ni < 4; ni++) acc2[mi][ni] = (floatx4){0.f, 0.f, 0.f, 0.f};
#pragma unroll
    for (int kc = 0; kc < 128; kc += 32) {
        short8 af[2], bfr[4];
#pragma unroll
        for (int mi = 0; mi < 2; mi++)
            af[mi] = *(const short8*)&h1s[(mb + mi * 16 + (l & 15)) * 136 + kc + (l >> 4) * 8];
#pragma unroll
        for (int ni = 0; ni < 4; ni++)
            bfr[ni] = *(const short8*)&w2s[(nb + ni * 16 + (l & 15)) * 136 + kc + (l >> 4) * 8];
#pragma unroll
        for (int mi = 0; mi < 2; mi++)
#pragma unroll
            for (int ni = 0; ni < 4; ni++)
                acc2[mi][ni] = __builtin_amdgcn_mfma_f32_16x16x32_bf16(
                    af[mi], bfr[ni], acc2[mi][ni], 0, 0, 0);
    }
    __syncthreads();   // done reading h1s; reuse region as h2s

    bf16* h2s = (bf16*)BIG;   // [64][136]
#pragma unroll
    for (int mi = 0; mi < 2; mi++)
#pragma unroll
        for (int r = 0; r < 4; r++) {
            int row = mb + mi * 16 + (l >> 4) * 4 + r;
#pragma unroll
            for (int ni = 0; ni < 4; ni++) {
                int col = nb + ni * 16 + (l & 15);
                float v = fmaxf(acc2[mi][ni][r] + b2s[col], 0.0f);
                h2s[row * 136 + col] = __float2bfloat16(v);
            }
        }
    __syncthreads();

    // phase 3: y tile via MFMA (wave w -> rows w*16..w*16+15)
    floatx4 acc3 = (floatx4){0.f, 0.f, 0.f, 0.f};
    int m3 = w * 16;
#pragma unroll
    for (int kc = 0; kc < 128; kc += 32) {
        short8 af = *(const short8*)&h2s[(m3 + (l & 15)) * 136 + kc + (l >> 4) * 8];
        short8 bf3 = *(const short8*)&w3ts[(l & 15) * 136 + kc + (l >> 4) * 8];
        acc3 = __builtin_amdgcn_mfma_f32_16x16x32_bf16(af, bf3, acc3, 0, 0, 0);
    }
    int col = l & 15;
    if (col < O_DIM) {
#pragma unroll
        for (int r = 0; r < 4; r++) {
            int row = m3 + (l >> 4) * 4 + r;
            if (row < mcnt)
                atomicAdd(&y[(size_t)rows_s[row] * O_DIM + col],
                          wts[row] * (acc3[r] + b3s[col]));
        }
    }
}

// ---------------------------------------------------------------------------
extern "C" void kernel_launch(void* const* d_in, const int* in_sizes, int n_in,
                              void* d_out, int out_size, void* d_ws, size_t ws_size,
                              hipStream_t stream) {
    (void)in_sizes; (void)n_in; (void)ws_size;
    const float* x      = (const float*)d_in[0];
    const float* gate_w = (const float*)d_in[1];
    const float* gate_b = (const float*)d_in[2];
    const float* w1     = (const float*)d_in[3];
    const float* b1     = (const float*)d_in[4];
    const float* w2     = (const float*)d_in[5];
    const float* b2     = (const float*)d_in[6];
    const float* w3     = (const float*)d_in[7];
    const float* b3     = (const float*)d_in[8];
    float* y = (float*)d_out;

    char* ws = (char*)d_ws;
    size_t off = 0;
    auto alloc = [&](size_t bytes) {
        void* p = ws + off;
        off = (off + bytes + 255) & ~(size_t)255;
        return p;
    };
    bf16*  x_bf16  = (bf16*)alloc((size_t)B_ROWS * D_DIM * 2);            // 100.7 MB
    bf16*  w1t     = (bf16*)alloc((size_t)E_NUM * H_DIM * D_DIM * 2);     // 6.3 MB
    bf16*  w2t     = (bf16*)alloc((size_t)E_NUM * H_DIM * H_DIM * 2);     // 0.26 MB
    int*   rowlist = (int*)alloc((size_t)E_NUM * B_ROWS * 4);
    float* wlist   = (float*)alloc((size_t)E_NUM * B_ROWS * 4);
    int*   gcnt    = (int*)alloc(64);

    hipMemsetAsync(d_out, 0, (size_t)out_size * sizeof(float), stream);
    hipMemsetAsync(gcnt, 0, 64, stream);

    transpose_bf16_kernel<<<dim3(D_DIM / 32, H_DIM / 32, E_NUM), dim3(32, 8), 0, stream>>>(
        w1, w1t, D_DIM, H_DIM);
    transpose_bf16_kernel<<<dim3(H_DIM / 32, H_DIM / 32, E_NUM), dim3(32, 8), 0, stream>>>(
        w2, w2t, H_DIM, H_DIM);
    gate_kernel<<<B_ROWS / 16, 256, 0, stream>>>(x, gate_w, gate_b, x_bf16,
                                                 rowlist, wlist, gcnt);
    expert_kernel<<<dim3(B_ROWS / 64, E_NUM), 256, 0, stream>>>(
        x_bf16, w1t, b1, w2t, b2, w3, b3, rowlist, wlist, gcnt, y);
}

// Round 5
// 495.125 us; speedup vs baseline: 1.2429x; 1.1115x over previous
//
#include <hip/hip_runtime.h>
#include <hip/hip_bf16.h>

#define B_ROWS 16384
#define D_DIM  3072
#define H_DIM  128
#define O_DIM  10
#define E_NUM  8

typedef __hip_bfloat16 bf16;
typedef __attribute__((ext_vector_type(8))) short short8;   // 8 bf16 = 4 VGPRs (MFMA A/B frag)
typedef __attribute__((ext_vector_type(4))) float floatx4;  // MFMA C/D frag

// ---------------------------------------------------------------------------
// K0: transpose+convert  in[e][R][C] fp32  ->  out[e][C][R] bf16
// ---------------------------------------------------------------------------
__global__ void transpose_bf16_kernel(const float* __restrict__ in,
                                      bf16* __restrict__ out, int R, int C) {
    int e = blockIdx.z;
    const float* inp = in + (size_t)e * R * C;
    bf16* outp = out + (size_t)e * R * C;
    __shared__ float tile[32][33];
    int tx = threadIdx.x;   // 0..31
    int ty = threadIdx.y;   // 0..7
    int r0 = blockIdx.x * 32, c0 = blockIdx.y * 32;
#pragma unroll
    for (int i = 0; i < 4; i++)
        tile[ty + i * 8][tx] = inp[(size_t)(r0 + ty + i * 8) * C + c0 + tx];
    __syncthreads();
#pragma unroll
    for (int i = 0; i < 4; i++)
        outp[(size_t)(c0 + ty + i * 8) * R + r0 + tx] =
            __float2bfloat16(tile[tx][ty + i * 8]);
}

// ---------------------------------------------------------------------------
// K1: gate v5. No LDS in main loop, no syncthreads: gate_w read directly from
// global (lane l reads 128 contiguous bytes = gate_w[dd..dd+3][0..7]; wave
// covers 8KB contiguous per j -> coalesced, L1/L2-resident after first touch).
// 4 rows/wave, 16 rows/block, 1024 blocks. fp32 math for top-k fidelity.
// ---------------------------------------------------------------------------
__global__ __launch_bounds__(256) void gate_kernel(
    const float* __restrict__ x, const float* __restrict__ gate_w,
    const float* __restrict__ gate_b, bf16* __restrict__ x_bf16,
    int* __restrict__ rowlist, float* __restrict__ wlist, int* __restrict__ gcnt)
{
    __shared__ int   eidx[16][2];
    __shared__ float ew[16][2];
    __shared__ int   lcnt[E_NUM], gbase[E_NUM];

    int t = threadIdx.x, w = t >> 6, l = t & 63;
    int rowblk = blockIdx.x * 16;
    int r0 = rowblk + w * 4;

    float4 accA[4], accB[4];   // experts 0-3 / 4-7 per row
#pragma unroll
    for (int r = 0; r < 4; r++) {
        accA[r] = (float4){0.f, 0.f, 0.f, 0.f};
        accB[r] = (float4){0.f, 0.f, 0.f, 0.f};
    }

#pragma unroll
    for (int j = 0; j < 12; j++) {
        int dd = j * 256 + l * 4;                   // lane's 4 d-rows
        const float4* gwp = (const float4*)(gate_w + (size_t)dd * 8);
        float4 g[8];                                 // g[2i],g[2i+1] = row dd+i
#pragma unroll
        for (int k = 0; k < 8; k++) g[k] = gwp[k];
#pragma unroll
        for (int r = 0; r < 4; r++) {
            size_t xi = (size_t)(r0 + r) * D_DIM + dd;
            float4 xv = *(const float4*)&x[xi];
            union { bf16 h[4]; uint2 v; } pk;
            pk.h[0] = __float2bfloat16(xv.x);
            pk.h[1] = __float2bfloat16(xv.y);
            pk.h[2] = __float2bfloat16(xv.z);
            pk.h[3] = __float2bfloat16(xv.w);
            *(uint2*)&x_bf16[xi] = pk.v;
            accA[r].x += xv.x * g[0].x + xv.y * g[2].x + xv.z * g[4].x + xv.w * g[6].x;
            accA[r].y += xv.x * g[0].y + xv.y * g[2].y + xv.z * g[4].y + xv.w * g[6].y;
            accA[r].z += xv.x * g[0].z + xv.y * g[2].z + xv.z * g[4].z + xv.w * g[6].z;
            accA[r].w += xv.x * g[0].w + xv.y * g[2].w + xv.z * g[4].w + xv.w * g[6].w;
            accB[r].x += xv.x * g[1].x + xv.y * g[3].x + xv.z * g[5].x + xv.w * g[7].x;
            accB[r].y += xv.x * g[1].y + xv.y * g[3].y + xv.z * g[5].y + xv.w * g[7].y;
            accB[r].z += xv.x * g[1].z + xv.y * g[3].z + xv.z * g[5].z + xv.w * g[7].z;
            accB[r].w += xv.x * g[1].w + xv.y * g[3].w + xv.z * g[5].w + xv.w * g[7].w;
        }
    }

    // butterfly reduce across 64 lanes
#pragma unroll
    for (int r = 0; r < 4; r++) {
        float s[8] = {accA[r].x, accA[r].y, accA[r].z, accA[r].w,
                      accB[r].x, accB[r].y, accB[r].z, accB[r].w};
#pragma unroll
        for (int e = 0; e < 8; e++) {
            float v = s[e];
#pragma unroll
            for (int off = 1; off < 64; off <<= 1) v += __shfl_xor(v, off, 64);
            s[e] = v;
        }
        accA[r] = (float4){s[0], s[1], s[2], s[3]};
        accB[r] = (float4){s[4], s[5], s[6], s[7]};
    }

    if (l == 0) {
#pragma unroll
        for (int r = 0; r < 4; r++) {
            float s[8] = {accA[r].x, accA[r].y, accA[r].z, accA[r].w,
                          accB[r].x, accB[r].y, accB[r].z, accB[r].w};
#pragma unroll
            for (int e = 0; e < 8; e++) s[e] += gate_b[e];
            // top-1 / top-2, strict > keeps lowest index on ties (lax.top_k)
            int i1 = 0; float m1 = s[0];
#pragma unroll
            for (int e = 1; e < 8; e++) if (s[e] > m1) { m1 = s[e]; i1 = e; }
            int i2 = -1; float m2 = -1e30f;
#pragma unroll
            for (int e = 0; e < 8; e++)
                if (e != i1 && s[e] > m2) { m2 = s[e]; i2 = e; }
            float S = 0.0f;
#pragma unroll
            for (int e = 0; e < 8; e++) S += expf(s[e] - m1);
            float p1 = expf(s[i1] - m1) / S;
            float p2 = expf(m2 - m1) / S;
            float denom = p1 + p2 + 1e-8f;
            eidx[w * 4 + r][0] = i1; ew[w * 4 + r][0] = p1 / denom;
            eidx[w * 4 + r][1] = i2; ew[w * 4 + r][1] = p2 / denom;
        }
    }
    __syncthreads();
    if (t < 8) lcnt[t] = 0;
    __syncthreads();
    int my_e = 0, my_lp = 0, my_rl = 0, my_sl = 0;
    if (t < 32) {
        my_rl = t >> 1; my_sl = t & 1;
        my_e = eidx[my_rl][my_sl];
        my_lp = atomicAdd(&lcnt[my_e], 1);
    }
    __syncthreads();
    if (t < 8) gbase[t] = atomicAdd(&gcnt[t], lcnt[t]);
    __syncthreads();
    if (t < 32) {
        int pos = gbase[my_e] + my_lp;
        rowlist[my_e * B_ROWS + pos] = rowblk + my_rl;
        wlist[my_e * B_ROWS + pos]   = ew[my_rl][my_sl];
    }
}

// ---------------------------------------------------------------------------
// K2: h1 = relu(x_gathered @ w1 + b1). 512 threads = 8 waves, BM=64 BN=128
// BK=64, wave-tile 16x64 (1x4 16x16x32 MFMA). LDS dbuf 55.5KB -> 2 blocks/CU
// = 16 waves/CU. One barrier per K-iter; register prefetch overlaps compute.
// ---------------------------------------------------------------------------
__global__ __launch_bounds__(512, 4) void gemm1_kernel(
    const bf16* __restrict__ xb, const bf16* __restrict__ w1t,
    const float* __restrict__ b1, const int* __restrict__ rowlist,
    const int* __restrict__ gcnt, bf16* __restrict__ h1buf)
{
    int e = blockIdx.y;
    int cnt = gcnt[e];
    int t0 = blockIdx.x * 64;
    if (t0 >= cnt) return;
    int mcnt = cnt - t0; if (mcnt > 64) mcnt = 64;

    __shared__ bf16 Ab[2][64][72];    // 18432 B  (+8 pad: 2-way conflicts only)
    __shared__ bf16 Bb[2][128][72];   // 36864 B
    __shared__ int rows_s[64];

    int t = threadIdx.x, w = t >> 6, l = t & 63;
    if (t < 64) {
        int rr = (t < mcnt) ? t : (mcnt - 1);
        rows_s[t] = rowlist[e * B_ROWS + t0 + rr];
    }
    __syncthreads();

    const bf16* w1base = w1t + (size_t)e * H_DIM * D_DIM;
    int ra = t >> 3, off8 = (t & 7) * 8;       // 64 rows x 8 chunks
    const bf16* aS  = xb + (size_t)rows_s[ra] * D_DIM + off8;
    const bf16* bS0 = w1base + (size_t)ra * D_DIM + off8;
    const bf16* bS1 = w1base + (size_t)(64 + ra) * D_DIM + off8;

    uint4 pa  = *(const uint4*)aS;
    uint4 pb0 = *(const uint4*)bS0;
    uint4 pb1 = *(const uint4*)bS1;

    int mb = (w & 3) * 16, nb = (w >> 2) * 64;

    floatx4 acc[4];
#pragma unroll
    for (int ni = 0; ni < 4; ni++) acc[ni] = (floatx4){0.f, 0.f, 0.f, 0.f};

    const int NKB = D_DIM / 64;   // 48
    for (int kb = 0; kb < NKB; kb++) {
        int bs = kb & 1;
        *(uint4*)&Ab[bs][ra][off8]      = pa;
        *(uint4*)&Bb[bs][ra][off8]      = pb0;
        *(uint4*)&Bb[bs][64 + ra][off8] = pb1;
        __syncthreads();
        if (kb + 1 < NKB) {                    // prefetch overlaps MFMA below
            int k0 = (kb + 1) * 64;
            pa  = *(const uint4*)(aS + k0);
            pb0 = *(const uint4*)(bS0 + k0);
            pb1 = *(const uint4*)(bS1 + k0);
        }
#pragma unroll
        for (int kc = 0; kc < 64; kc += 32) {
            short8 af = *(const short8*)&Ab[bs][mb + (l & 15)][kc + (l >> 4) * 8];
            short8 bfr[4];
#pragma unroll
            for (int ni = 0; ni < 4; ni++)
                bfr[ni] = *(const short8*)&Bb[bs][nb + ni * 16 + (l & 15)][kc + (l >> 4) * 8];
#pragma unroll
            for (int ni = 0; ni < 4; ni++)
                acc[ni] = __builtin_amdgcn_mfma_f32_16x16x32_bf16(af, bfr[ni], acc[ni], 0, 0, 0);
        }
    }

    // epilogue: D row = (l>>4)*4 + reg, col = l&15 (measured C/D layout)
#pragma unroll
    for (int r = 0; r < 4; r++) {
        int row = mb + (l >> 4) * 4 + r;
        if (row < mcnt) {
#pragma unroll
            for (int ni = 0; ni < 4; ni++) {
                int col = nb + ni * 16 + (l & 15);
                float v = fmaxf(acc[ni][r] + b1[e * H_DIM + col], 0.0f);
                h1buf[(size_t)e * B_ROWS * H_DIM + (size_t)(t0 + row) * H_DIM + col] =
                    __float2bfloat16(v);
            }
        }
    }
}

// ---------------------------------------------------------------------------
// K3: h2 = relu(h1 @ w2 + b2); y[row] += weight * (h2 @ w3 + b3).
// 256 threads = 4 waves, 64 compacted rows/block. h1 tile + w2 in LDS; final
// y-tile via MFMA against zero-padded 16x128 transposed w3.
// ---------------------------------------------------------------------------
__global__ __launch_bounds__(256) void gemm2c_kernel(
    const bf16* __restrict__ h1buf, const bf16* __restrict__ w2t,
    const float* __restrict__ b2, const float* __restrict__ w3,
    const float* __restrict__ b3, const int* __restrict__ rowlist,
    const float* __restrict__ wlist, const int* __restrict__ gcnt,
    float* __restrict__ y)
{
    int e = blockIdx.y;
    int cnt = gcnt[e];
    int t0 = blockIdx.x * 64;
    if (t0 >= cnt) return;
    int mcnt = cnt - t0; if (mcnt > 64) mcnt = 64;

    __shared__ bf16 h1s[64][136];     // 17408 B; reused as h2s
    __shared__ bf16 w2s[128][136];    // 34816 B
    __shared__ bf16 w3ts[16 * 136];   // 4352 B
    __shared__ float b2s[H_DIM], b3s[16], wts[64];
    __shared__ int rows_s[64];

    int t = threadIdx.x, w = t >> 6, l = t & 63;

    if (t < 64) {
        int rr = (t < mcnt) ? t : (mcnt - 1);
        rows_s[t] = rowlist[e * B_ROWS + t0 + rr];
        wts[t]    = wlist[e * B_ROWS + t0 + rr];
    }
    if (t < H_DIM) b2s[t] = b2[e * H_DIM + t];
    if (t < O_DIM) b3s[t] = b3[e * O_DIM + t];
    // w3ts[o][h] = w3[e][h][o], rows 10..15 zero
    for (int idx = t; idx < H_DIM * O_DIM; idx += 256)
        w3ts[(idx % 10) * 136 + idx / 10] = __float2bfloat16(w3[(size_t)e * H_DIM * O_DIM + idx]);
    for (int idx = t; idx < 6 * 128; idx += 256)
        w3ts[(10 + idx / 128) * 136 + (idx % 128)] = __float2bfloat16(0.0f);

    // stage h1 tile (64 rows x 128 cols; rows >= mcnt hold stale data, guarded
    // at scatter) and w2 (128x128)
    {
        const bf16* h1base = h1buf + (size_t)e * B_ROWS * H_DIM + (size_t)t0 * H_DIM;
        int hend = mcnt * 16;   // 16 chunks of 16B per row
#pragma unroll
        for (int k = 0; k < 4; k++) {
            int si = t + 256 * k;                   // 0..1023
            if (si < hend)
                *(uint4*)&h1s[si >> 4][(si & 15) * 8] =
                    *(const uint4*)(h1base + (size_t)(si >> 4) * H_DIM + (si & 15) * 8);
        }
        const bf16* w2base = w2t + (size_t)e * H_DIM * H_DIM;
#pragma unroll
        for (int k = 0; k < 8; k++) {
            int si = t + 256 * k;                   // 0..2047
            *(uint4*)&w2s[si >> 4][(si & 15) * 8] =
                *(const uint4*)(w2base + (size_t)(si >> 4) * H_DIM + (si & 15) * 8);
        }
    }
    __syncthreads();

    int mb = (w & 1) * 32, nb = (w >> 1) * 64;
    floatx4 acc2[2][4];
#pragma unroll
    for (int mi = 0; mi < 2; mi++)
#pragma unroll
        for (int ni = 0; ni < 4; ni++) acc2[mi][ni] = (floatx4){0.f, 0.f, 0.f, 0.f};
#pragma unroll
    for (int kc = 0; kc < 128; kc += 32) {
        short8 af[2], bfr[4];
#pragma unroll
        for (int mi = 0; mi < 2; mi++)
            af[mi] = *(const short8*)&h1s[mb + mi * 16 + (l & 15)][kc + (l >> 4) * 8];
#pragma unroll
        for (int ni = 0; ni < 4; ni++)
            bfr[ni] = *(const short8*)&w2s[nb + ni * 16 + (l & 15)][kc + (l >> 4) * 8];
#pragma unroll
        for (int mi = 0; mi < 2; mi++)
#pragma unroll
            for (int ni = 0; ni < 4; ni++)
                acc2[mi][ni] = __builtin_amdgcn_mfma_f32_16x16x32_bf16(
                    af[mi], bfr[ni], acc2[mi][ni], 0, 0, 0);
    }
    __syncthreads();   // all reads of h1s done; reuse as h2s

    bf16* h2s = &h1s[0][0];
#pragma unroll
    for (int mi = 0; mi < 2; mi++)
#pragma unroll
        for (int r = 0; r < 4; r++) {
            int row = mb + mi * 16 + (l >> 4) * 4 + r;
#pragma unroll
            for (int ni = 0; ni < 4; ni++) {
                int col = nb + ni * 16 + (l & 15);
                float v = fmaxf(acc2[mi][ni][r] + b2s[col], 0.0f);
                h2s[row * 136 + col] = __float2bfloat16(v);
            }
        }
    __syncthreads();

    // y tile via MFMA (wave w -> rows w*16..w*16+15)
    floatx4 acc3 = (floatx4){0.f, 0.f, 0.f, 0.f};
    int m3 = w * 16;
#pragma unroll
    for (int kc = 0; kc < 128; kc += 32) {
        short8 af  = *(const short8*)&h2s[(m3 + (l & 15)) * 136 + kc + (l >> 4) * 8];
        short8 bf3 = *(const short8*)&w3ts[(l & 15) * 136 + kc + (l >> 4) * 8];
        acc3 = __builtin_amdgcn_mfma_f32_16x16x32_bf16(af, bf3, acc3, 0, 0, 0);
    }
    int col = l & 15;
    if (col < O_DIM) {
#pragma unroll
        for (int r = 0; r < 4; r++) {
            int row = m3 + (l >> 4) * 4 + r;
            if (row < mcnt)
                atomicAdd(&y[(size_t)rows_s[row] * O_DIM + col],
                          wts[row] * (acc3[r] + b3s[col]));
        }
    }
}

// ---------------------------------------------------------------------------
extern "C" void kernel_launch(void* const* d_in, const int* in_sizes, int n_in,
                              void* d_out, int out_size, void* d_ws, size_t ws_size,
                              hipStream_t stream) {
    (void)in_sizes; (void)n_in; (void)ws_size;
    const float* x      = (const float*)d_in[0];
    const float* gate_w = (const float*)d_in[1];
    const float* gate_b = (const float*)d_in[2];
    const float* w1     = (const float*)d_in[3];
    const float* b1     = (const float*)d_in[4];
    const float* w2     = (const float*)d_in[5];
    const float* b2     = (const float*)d_in[6];
    const float* w3     = (const float*)d_in[7];
    const float* b3     = (const float*)d_in[8];
    float* y = (float*)d_out;

    char* ws = (char*)d_ws;
    size_t off = 0;
    auto alloc = [&](size_t bytes) {
        void* p = ws + off;
        off = (off + bytes + 255) & ~(size_t)255;
        return p;
    };
    bf16*  x_bf16  = (bf16*)alloc((size_t)B_ROWS * D_DIM * 2);            // 100.7 MB
    bf16*  w1t     = (bf16*)alloc((size_t)E_NUM * H_DIM * D_DIM * 2);     // 6.3 MB
    bf16*  w2t     = (bf16*)alloc((size_t)E_NUM * H_DIM * H_DIM * 2);     // 0.26 MB
    bf16*  h1buf   = (bf16*)alloc((size_t)E_NUM * B_ROWS * H_DIM * 2);    // 33.6 MB
    int*   rowlist = (int*)alloc((size_t)E_NUM * B_ROWS * 4);
    float* wlist   = (float*)alloc((size_t)E_NUM * B_ROWS * 4);
    int*   gcnt    = (int*)alloc(64);

    hipMemsetAsync(d_out, 0, (size_t)out_size * sizeof(float), stream);
    hipMemsetAsync(gcnt, 0, 64, stream);

    transpose_bf16_kernel<<<dim3(D_DIM / 32, H_DIM / 32, E_NUM), dim3(32, 8), 0, stream>>>(
        w1, w1t, D_DIM, H_DIM);
    transpose_bf16_kernel<<<dim3(H_DIM / 32, H_DIM / 32, E_NUM), dim3(32, 8), 0, stream>>>(
        w2, w2t, H_DIM, H_DIM);
    gate_kernel<<<B_ROWS / 16, 256, 0, stream>>>(x, gate_w, gate_b, x_bf16,
                                                 rowlist, wlist, gcnt);
    gemm1_kernel<<<dim3(B_ROWS / 64, E_NUM), 512, 0, stream>>>(
        x_bf16, w1t, b1, rowlist, gcnt, h1buf);
    gemm2c_kernel<<<dim3(B_ROWS / 64, E_NUM), 256, 0, stream>>>(
        h1buf, w2t, b2, w3, b3, rowlist, wlist, gcnt, y);
}